// Round 5
// baseline (286.983 us; speedup 1.0000x reference)
//
#include <hip/hip_runtime.h>
#include <hip/hip_fp16.h>
#include <cstdint>

#define D 128
#define NLEV 16
#define TPB 512
#define WPB 8            // waves per block
#define ROWS_PER_WAVE 16
#define ROWS_PER_BLOCK (WPB * ROWS_PER_WAVE)  // 128

typedef __attribute__((ext_vector_type(8))) short bf16x8;  // MFMA A/B frag (4 VGPR)
typedef __attribute__((ext_vector_type(4))) float f32x4;   // MFMA C/D frag

__device__ __forceinline__ float sload_f(float v) {
    return __int_as_float(__builtin_amdgcn_readfirstlane(__float_as_int(v)));
}
__device__ __forceinline__ unsigned short f32_bf16(float f) {  // RNE
    uint32_t u = __float_as_uint(f);
    return (unsigned short)((u + 0x7fffu + ((u >> 16) & 1u)) >> 16);
}
__device__ __forceinline__ float bf16_f32(unsigned short h) {
    return __uint_as_float(((uint32_t)h) << 16);
}

// ---- K0: prepack PiTpair (phase-1 LDS layout) + hi/lo bf16 MFMA-B frags ----
// PiTpair[jp][l][q] (jp=0..63, l=0..63, q=0..3):
//   q0=Pi[2l][2jp] q1=Pi[2l+1][2jp] q2=Pi[2l][2jp+1] q3=Pi[2l+1][2jp+1]
// -> phase 1 reads one ds_read_b128 per j-pair, natural conflict-free pattern.
// B-frag layout (16x16x32): lane l supplies B[(l>>4)*8+e][l&15]; frag (it,kf)
// covers n=it*16..+15, k=kf*32..+31. Stored fragment-major for b128 reads.
__global__ void tq_prepack(const float* __restrict__ Pi, float* __restrict__ PiTpair,
                           unsigned short* __restrict__ Bhi, unsigned short* __restrict__ Blo) {
    const int t = blockIdx.x * blockDim.x + threadIdx.x;  // 0..16383
    {
        const int q = t & 3, l = (t >> 2) & 63, jp = t >> 8;
        PiTpair[t] = Pi[(2 * l + (q & 1)) * D + (2 * jp + (q >> 1))];
    }
    const int e = t & 7, l = (t >> 3) & 63, f = t >> 9;   // f = it*4+kf (0..31)
    const int kf = f & 3, it = f >> 2;
    const int k = kf * 32 + (l >> 4) * 8 + e;
    const int i = it * 16 + (l & 15);
    const float v = Pi[k * D + i];
    const unsigned short hi = f32_bf16(v);
    Bhi[t] = hi;
    Blo[t] = f32_bf16(v - bf16_f32(hi));
}

// ---- K1: compress (fp32 VALU, bit-identical to R4) + decompress (bf16 MFMA) ----
__global__ __launch_bounds__(TPB, 2)
void tq_main(const float* __restrict__ x, const float* __restrict__ PiTpair,
             const unsigned short* __restrict__ Bhi, const unsigned short* __restrict__ Blo,
             const float* __restrict__ cbk, float* __restrict__ out, int nrows) {
    __shared__ uint32_t lds_u[8192];        // 32 KiB: PiTpair half-tiles, then packed codes
    float* ldsP = (float*)lds_u;

    const int tid  = threadIdx.x;
    const int lane = tid & 63;
    const int wave = tid >> 6;

    // codebook + decision boundaries, wave-uniform (SGPR)
    float code[NLEV], mid[NLEV - 1];
#pragma unroll
    for (int k = 0; k < NLEV; ++k) code[k] = sload_f(cbk[k]);
#pragma unroll
    for (int k = 0; k < NLEV - 1; ++k) mid[k] = 0.5f * (code[k] + code[k + 1]);

    const float sqrt_d = 11.313708498984761f;  // sqrt(128)

    int row0 = (blockIdx.x * WPB + wave) * ROWS_PER_WAVE;
    if (row0 > nrows - ROWS_PER_WAVE) row0 = nrows - ROWS_PER_WAVE;  // defensive; grid is exact

    // ---- norms (same load + reduction order as R4; xv dies after this) ----
    float ns[ROWS_PER_WAVE];
    {
        float2 xv[ROWS_PER_WAVE];
#pragma unroll
        for (int r = 0; r < ROWS_PER_WAVE; ++r)
            xv[r] = *reinterpret_cast<const float2*>(x + (size_t)(row0 + r) * D + 2 * lane);
#pragma unroll
        for (int r = 0; r < ROWS_PER_WAVE; ++r) {
            float s = fmaf(xv[r].x, xv[r].x, xv[r].y * xv[r].y);
#pragma unroll
            for (int off = 32; off; off >>= 1) s += __shfl_xor(s, off, 64);
            ns[r] = s;
        }
    }

    float y0[ROWS_PER_WAVE], y1[ROWS_PER_WAVE];
#pragma unroll
    for (int r = 0; r < ROWS_PER_WAVE; ++r) { y0[r] = 0.f; y1[r] = 0.f; }

    const float* xw = x + (size_t)row0 * D;  // wave's row block (rows contiguous)

    // ---- matvec1: y_i = sum_j Pi[i][j] x[j], lane owns i=2l,2l+1 ----
    // x[row][j] is wave-uniform -> broadcast via uniform-address vector load
    // (VMEM/L1 pipe), replacing 32 v_readlane per j-pair on the VALU pipe.
    // FMA order per row is IDENTICAL to R2-R4 (bit-exact y).
    for (int h = 0; h < 2; ++h) {
        __syncthreads();  // previous LDS contents no longer needed
        {
            const float4* src = reinterpret_cast<const float4*>(PiTpair + h * 8192);
            float4* dst = reinterpret_cast<float4*>(ldsP);
#pragma unroll
            for (int k = 0; k < 4; ++k) dst[tid + k * TPB] = src[tid + k * TPB];
        }
        __syncthreads();
#pragma unroll 2
        for (int jp = 0; jp < 32; ++jp) {
            const float4 p = reinterpret_cast<const float4*>(ldsP)[jp * 64 + lane];
            const int j = h * 64 + jp * 2;
#pragma unroll
            for (int r = 0; r < ROWS_PER_WAVE; ++r) {
                const float2 xj = *reinterpret_cast<const float2*>(xw + r * D + j);
                y0[r] = fmaf(p.x, xj.x, y0[r]);
                y1[r] = fmaf(p.y, xj.x, y1[r]);
                y0[r] = fmaf(p.z, xj.y, y0[r]);
                y1[r] = fmaf(p.w, xj.y, y1[r]);
            }
        }
    }

    // ---- quantize (identical math/order to R4) ----
    uint32_t cpk[ROWS_PER_WAVE];
#pragma unroll
    for (int r = 0; r < ROWS_PER_WAVE; ++r) {
        const float nrm = sqrtf(ns[r]);
        const float s1  = sqrt_d / fmaxf(nrm, 1e-8f);
        const float hh  = __half2float(__float2half(nrm));
        const float sc  = hh / sqrt_d;
        const float ya = y0[r] * s1;
        const float yb = y1[r] * s1;
        float ca = code[0], cb2 = code[0];
#pragma unroll
        for (int k = 0; k < NLEV - 1; ++k) {
            ca  = (ya > mid[k]) ? code[k + 1] : ca;
            cb2 = (yb > mid[k]) ? code[k + 1] : cb2;
        }
        const unsigned short ha = __half_as_ushort(__float2half(ca * sc));
        const unsigned short hb = __half_as_ushort(__float2half(cb2 * sc));
        cpk[r] = (uint32_t)ha | ((uint32_t)hb << 16);
    }

    __syncthreads();  // all PiTpair reads done before overwriting LDS with codes

    // ---- codes -> LDS (XOR-swizzled rows; read back as MFMA A-frags) ----
#pragma unroll
    for (int r = 0; r < ROWS_PER_WAVE; ++r) {
        lds_u[(wave * 16 + r) * 64 + (lane ^ ((r & 7) << 2))] = cpk[r];
    }
    __syncthreads();

    // ---- phase 2: out[16 x 128] = codes @ Pi via split-bf16 MFMA (verbatim R4) ----
    const int m  = lane & 15;   // A row / D col
    const int kb = lane >> 4;   // k-subblock / D row-block
    bf16x8 ahi[4], alo[4];
#pragma unroll
    for (int kf = 0; kf < 4; ++kf) {
        const int idx = (wave * 16 + m) * 64 + ((kf * 16 + kb * 4) ^ ((m & 7) << 2));
        const uint4 u = *reinterpret_cast<const uint4*>(lds_u + idx);
#pragma unroll
        for (int q = 0; q < 4; ++q) {
            const uint32_t w = ((const uint32_t*)&u)[q];
            const float f0 = __half2float(__ushort_as_half((unsigned short)(w & 0xffffu)));
            const float f1 = __half2float(__ushort_as_half((unsigned short)(w >> 16)));
            const unsigned short h0 = f32_bf16(f0);
            const unsigned short h1 = f32_bf16(f1);
            ahi[kf][2 * q]     = (short)h0;
            ahi[kf][2 * q + 1] = (short)h1;
            alo[kf][2 * q]     = (short)f32_bf16(f0 - bf16_f32(h0));  // exact residual of fp16 value
            alo[kf][2 * q + 1] = (short)f32_bf16(f1 - bf16_f32(h1));
        }
    }
#pragma unroll
    for (int it = 0; it < 8; ++it) {
        f32x4 a = {0.f, 0.f, 0.f, 0.f};
#pragma unroll
        for (int kf = 0; kf < 4; ++kf) {
            const size_t fi = (size_t)((it * 4 + kf) * 64 + lane) * 8;
            const bf16x8 bh = *reinterpret_cast<const bf16x8*>(Bhi + fi);
            const bf16x8 bl = *reinterpret_cast<const bf16x8*>(Blo + fi);
            a = __builtin_amdgcn_mfma_f32_16x16x32_bf16(ahi[kf], bh, a, 0, 0, 0);
            a = __builtin_amdgcn_mfma_f32_16x16x32_bf16(alo[kf], bh, a, 0, 0, 0);
            a = __builtin_amdgcn_mfma_f32_16x16x32_bf16(ahi[kf], bl, a, 0, 0, 0);
        }
#pragma unroll
        for (int reg = 0; reg < 4; ++reg) {
            const int row = row0 + kb * 4 + reg;       // C/D: row=(lane>>4)*4+reg  [m89]
            if (row < nrows) out[(size_t)row * D + it * 16 + m] = a[reg];
        }
    }
}

extern "C" void kernel_launch(void* const* d_in, const int* in_sizes, int n_in,
                              void* d_out, int out_size, void* d_ws, size_t ws_size,
                              hipStream_t stream) {
    const float* x   = (const float*)d_in[0];
    const float* Pi  = (const float*)d_in[1];
    const float* cbk = (const float*)d_in[2];
    float* out = (float*)d_out;

    float*          PiTpair = (float*)d_ws;                           // 64 KiB
    unsigned short* Bhi = (unsigned short*)((char*)d_ws + 65536);     // 32 KiB
    unsigned short* Blo = (unsigned short*)((char*)d_ws + 98304);     // 32 KiB

    const int nrows = in_sizes[0] / D;
    const int grid  = (nrows + ROWS_PER_BLOCK - 1) / ROWS_PER_BLOCK;

    tq_prepack<<<dim3(64), dim3(256), 0, stream>>>(Pi, PiTpair, Bhi, Blo);
    tq_main<<<dim3(grid), dim3(TPB), 0, stream>>>(x, PiTpair, Bhi, Blo, cbk, out, nrows);
}